// Round 15
// baseline (63.593 us; speedup 1.0000x reference)
//
#include <hip/hip_runtime.h>
#include <math.h>

typedef __attribute__((ext_vector_type(8))) short short8;
typedef __attribute__((ext_vector_type(4))) float f32x4;

#define DT_STEP 0.1f

static __device__ __forceinline__ unsigned bf16rne(float f) {
    unsigned u = __builtin_bit_cast(unsigned, f);
    return (u + 0x7fffu + ((u >> 16) & 1u)) >> 16;
}
static __device__ __forceinline__ unsigned short bf16pk1(float f) {
    unsigned r;
    asm("v_cvt_pk_bf16_f32 %0, %1, %1" : "=v"(r) : "v"(f));
    return (unsigned short)r;
}
static __device__ __forceinline__ unsigned bf16pk2(float lo, float hi) {
    unsigned r;
    asm("v_cvt_pk_bf16_f32 %0, %1, %2" : "=v"(r) : "v"(lo), "v"(hi));
    return r;
}
static __device__ __forceinline__ float tanh_fast(float v) {
    float e = __expf(2.0f * v);
    return 1.0f - 2.0f / (e + 1.0f);
}

static __device__ __forceinline__ void mm3(const float* A, const float* B, float* C) {
#pragma unroll
    for (int i = 0; i < 3; ++i)
#pragma unroll
        for (int j = 0; j < 3; ++j)
            C[i * 3 + j] = A[i * 3 + 0] * B[0 * 3 + j] + A[i * 3 + 1] * B[1 * 3 + j] + A[i * 3 + 2] * B[2 * 3 + j];
}
static __device__ __forceinline__ void mv3(const float* A, const float* x, float* y) {
#pragma unroll
    for (int i = 0; i < 3; ++i) y[i] = A[i * 3 + 0] * x[0] + A[i * 3 + 1] * x[1] + A[i * 3 + 2] * x[2];
}
static __device__ __forceinline__ void mtv3(const float* A, const float* x, float* y) {
#pragma unroll
    for (int i = 0; i < 3; ++i) y[i] = A[0 * 3 + i] * x[0] + A[1 * 3 + i] * x[1] + A[2 * 3 + i] * x[2];
}
static __device__ __forceinline__ void cross3(const float* p, const float* u, float* y) {
    y[0] = p[1] * u[2] - p[2] * u[1];
    y[1] = p[2] * u[0] - p[0] * u[2];
    y[2] = p[0] * u[1] - p[1] * u[0];
}

// ws layout (unsigned short elements) — verified r6/r7/r9/r10/r13:
//  [0,4096)      W1A: [n1=128][k=32] bf16, k>=12 zero
//  [4096,20480)  W2B: [n2=128][k=128] bf16
//  [20480,22528) W3B: [(kt*4+lg)*16 + n3pad]*8, n3pad<6 valid else 0
__global__ __launch_bounds__(256)
void weights_prep(const float* __restrict__ W1, const float* __restrict__ W2,
                  const float* __restrict__ W3, unsigned short* __restrict__ ws) {
    int i = blockIdx.x * 256 + threadIdx.x;
    if (i < 4096) {
        int n = i >> 5, k = i & 31;
        ws[i] = (k < 12) ? (unsigned short)bf16rne(W1[n * 12 + k]) : (unsigned short)0;
    } else if (i < 20480) {
        ws[i] = (unsigned short)bf16rne(W2[i - 4096]);
    } else if (i < 22528) {
        int j = i - 20480;
        int jj = j & 7;
        int l = (j >> 3) & 15;     // n3 (valid < 6)
        int kl = j >> 7;           // kt*4+lg
        int k = kl * 8 + jj;
        ws[i] = (l < 6) ? (unsigned short)bf16rne(W3[l * 128 + k]) : (unsigned short)0;
    }
}

// r13 (best verified, 52.5us) with phase fusion to kill serial latency gaps:
//  - all 8 W1A b1 fragments preloaded before the P2 loop (no per-nt L2 stall);
//  - P3 folded into P2: af2[*][kt] read right after store-iteration nt=2kt+1
//    (columns complete; regular DS ops, in-order pipe, may-alias keeps order);
//  - P5 folded into P4 the same way; SE3 part-1 covers residual af3 latency.
// All LDS/fragment data paths byte-identical to r13. launch_bounds(64,2):
// VGPR cap 256 (peak live ~200); LDS 18432 -> 8 blocks/CU regardless.
__global__ __launch_bounds__(64, 2)
void auv_mfma12_kernel(const float* __restrict__ s, const float* __restrict__ a,
                       const float* __restrict__ h0, const float* __restrict__ W_ih,
                       const float* __restrict__ W_hh, const unsigned short* __restrict__ Wbf,
                       float* __restrict__ out, int K)
{
    __shared__ __align__(16) char lds[18432];
    const int lane = threadIdx.x & 63;
    const int l15  = lane & 15;
    const int lg   = lane >> 4;

    char* l12 = &lds[0];            // 64 rows x 256B, XOR swizzle ((row&15)<<4)
    char* h1t = &lds[16384];        // 64 rows x 32B
    char* dvt = &lds[0];            // overlay after af3 reads

    const unsigned short* W1A = Wbf;
    const unsigned short* W2B = Wbf + 4096;
    const unsigned short* W3B = Wbf + 20480;

    const int e_raw = blockIdx.x * 64 + lane;
    const int e  = e_raw < K ? e_raw : K - 1;
    const bool live = e_raw < K;

    const float* srow = s  + (size_t)e * 18;
    const float* arow = a  + (size_t)e * 6;
    const float* hrow = h0 + (size_t)e * 12;

    // ---------------- Phase 1: RNN (scalar; W rows wave-uniform -> s_load) ----------------
    float pv3[3];
    pv3[0] = srow[0]; pv3[1] = srow[1]; pv3[2] = srow[2];
    float xv[21];
#pragma unroll
    for (int i = 0; i < 15; ++i) xv[i] = srow[3 + i];
#pragma unroll
    for (int i = 0; i < 6; ++i)  xv[15 + i] = arow[i];
    float h0v[12];
#pragma unroll
    for (int i = 0; i < 12; ++i) h0v[i] = hrow[i];

    float h1v[12];
#pragma unroll
    for (int j = 0; j < 12; ++j) {
        float acc = 0.f;
        const float* wih = W_ih + j * 21;
#pragma unroll
        for (int i = 0; i < 21; ++i) acc = fmaf(wih[i], xv[i], acc);
        const float* whh = W_hh + j * 12;
#pragma unroll
        for (int i = 0; i < 12; ++i) acc = fmaf(whh[i], h0v[i], acc);
        h1v[j] = tanh_fast(acc);
    }

    if (live) {
        float4* h4 = (float4*)(out + (size_t)K * 18 + (size_t)e * 12);
        h4[0] = make_float4(h1v[0], h1v[1], h1v[2], h1v[3]);
        h4[1] = make_float4(h1v[4], h1v[5], h1v[6], h1v[7]);
        h4[2] = make_float4(h1v[8], h1v[9], h1v[10], h1v[11]);
    }

    // T14: issue W2B nt=0 B-frag loads NOW (consumed in P4)
    short8 bfr[4];
#pragma unroll
    for (int kt = 0; kt < 4; ++kt)
        bfr[kt] = __builtin_bit_cast(short8,
            *(const uint4*)(W2B + (l15 * 128 + kt * 32 + lg * 8)));

    // h1 -> h1t: row=lane, 16 bf16 (12 valid + 4 zero); chunk swizzle by (row&1)
    {
        unsigned p0 = bf16pk2(h1v[0], h1v[1]);
        unsigned p1 = bf16pk2(h1v[2], h1v[3]);
        unsigned p2 = bf16pk2(h1v[4], h1v[5]);
        unsigned p3 = bf16pk2(h1v[6], h1v[7]);
        unsigned p4 = bf16pk2(h1v[8], h1v[9]);
        unsigned p5 = bf16pk2(h1v[10], h1v[11]);
        int rq = (lane & 1) << 4;
        *(uint4*)(h1t + lane * 32 + (0 ^ rq))  = make_uint4(p0, p1, p2, p3);
        *(uint4*)(h1t + lane * 32 + (16 ^ rq)) = make_uint4(p4, p5, 0u, 0u);
    }

    const short8 zfrag = {0, 0, 0, 0, 0, 0, 0, 0};

    // ---------------- Phase 2 (+fused P3): Layer 1 MFMA + af2 reads ----------------
    short8 af1[4];
#pragma unroll
    for (int rt = 0; rt < 4; ++rt) {
        af1[rt] = zfrag;
        if (lg < 2) {
            int row = rt * 16 + l15;
            af1[rt] = __builtin_bit_cast(short8,
                *(const uint4*)(h1t + row * 32 + ((lg * 16) ^ ((row & 1) << 4))));
        }
    }

    // preload ALL W1A b1 fragments (32 VGPR; loads overlap af1 LDS latency)
    short8 b1all[8];
#pragma unroll
    for (int nt = 0; nt < 8; ++nt)
        b1all[nt] = __builtin_bit_cast(short8,
            *(const uint4*)(W1A + ((nt * 16 + l15) * 32 + lg * 8)));

    short8 af2[4][4];
#pragma unroll
    for (int nt = 0; nt < 8; ++nt) {      // full unroll: static nt for af2 index
#pragma unroll
        for (int rt = 0; rt < 4; ++rt) {
            f32x4 z = {0.f, 0.f, 0.f, 0.f};
            f32x4 c1 = __builtin_amdgcn_mfma_f32_16x16x32_bf16(af1[rt], b1all[nt], z, 0, 0, 0);
#pragma unroll
            for (int r = 0; r < 4; ++r) {
                int row = rt * 16 + lg * 4 + r;
                float v = c1[r];
                v = fmaxf(v, 0.1f * v);
                *(unsigned short*)(l12 + row * 256 +
                    (((nt * 16 + l15) * 2) ^ ((row & 15) << 4))) = bf16pk1(v);
            }
        }
        if (nt & 1) {                     // columns kt=nt>>1 now complete -> read
            const int kt = nt >> 1;
#pragma unroll
            for (int rt = 0; rt < 4; ++rt) {
                int row = rt * 16 + l15;
                af2[rt][kt] = __builtin_bit_cast(short8,
                    *(const uint4*)(l12 + row * 256 + ((kt * 64 + lg * 16) ^ ((row & 15) << 4))));
            }
        }
    }

    // T14: W3B loads issued early (consumed in P6)
    short8 b3f[4];
#pragma unroll
    for (int kt = 0; kt < 4; ++kt)
        b3f[kt] = __builtin_bit_cast(short8,
            *(const uint4*)(W3B + (((kt * 4 + lg) * 16 + l15) * 8)));

    // ---------------- Phase 4 (+fused P5): Layer 2 MFMA + af3 reads ----------------
    short8 af3[4][4];
#pragma unroll
    for (int nt = 0; nt < 8; ++nt) {
        short8 bnext[4];
        if (nt < 7) {
#pragma unroll
            for (int kt = 0; kt < 4; ++kt)
                bnext[kt] = __builtin_bit_cast(short8,
                    *(const uint4*)(W2B + (((nt + 1) * 16 + l15) * 128 + kt * 32 + lg * 8)));
        }
#pragma unroll
        for (int rt = 0; rt < 4; ++rt) {
            f32x4 c2 = {0.f, 0.f, 0.f, 0.f};
#pragma unroll
            for (int kt = 0; kt < 4; ++kt)
                c2 = __builtin_amdgcn_mfma_f32_16x16x32_bf16(af2[rt][kt], bfr[kt], c2, 0, 0, 0);
#pragma unroll
            for (int r = 0; r < 4; ++r) {
                int row = rt * 16 + lg * 4 + r;
                float v = c2[r];
                v = fmaxf(v, 0.1f * v);
                *(unsigned short*)(l12 + row * 256 +
                    (((nt * 16 + l15) * 2) ^ ((row & 15) << 4))) = bf16pk1(v);
            }
        }
#pragma unroll
        for (int kt = 0; kt < 4; ++kt) bfr[kt] = bnext[kt];
        if (nt & 1) {                     // l2 columns kt=nt>>1 complete -> read
            const int kt = nt >> 1;
#pragma unroll
            for (int rt = 0; rt < 4; ++rt) {
                int row = rt * 16 + l15;
                af3[rt][kt] = __builtin_bit_cast(short8,
                    *(const uint4*)(l12 + row * 256 + ((kt * 64 + lg * 16) ^ ((row & 15) << 4))));
            }
        }
    }

    // ---------------- SE3 part 1 (covers residual af3 latency) ----------------
    const float* v = &xv[9];
    const float* p = pv3;
    const float* R = &xv[0];

    float Rn[9], pn[3], pinv[3], Rvl[3], Rva[3], px[3];
    {
        float rho[3] = {v[0] * DT_STEP, v[1] * DT_STEP, v[2] * DT_STEP};
        float phi[3] = {v[3] * DT_STEP, v[4] * DT_STEP, v[5] * DT_STEP};
        float th2 = phi[0] * phi[0] + phi[1] * phi[1] + phi[2] * phi[2];

        float A, B, C;
        if (th2 < 1e-8f) {
            A = 1.0f - th2 * (1.0f / 6.0f);
            B = 0.5f - th2 * (1.0f / 24.0f);
            C = (1.0f / 6.0f) - th2 * (1.0f / 120.0f);
        } else {
            float th = sqrtf(th2);
            float sn = sinf(th), cs = cosf(th);
            A = sn / th;
            B = (1.0f - cs) / th2;
            C = (th - sn) / (th2 * th);
        }

        float S[9] = {0.f, -phi[2], phi[1], phi[2], 0.f, -phi[0], -phi[1], phi[0], 0.f};
        float S2[9];
        mm3(S, S, S2);

        float Re[9], V[9];
#pragma unroll
        for (int i = 0; i < 9; ++i) {
            float I = (i == 0 || i == 4 || i == 8) ? 1.0f : 0.0f;
            Re[i] = I + A * S[i] + B * S2[i];
            V[i]  = I + B * S[i] + C * S2[i];
        }

        float pe[3];
        mv3(V, rho, pe);
        mm3(R, Re, Rn);
        mv3(R, pe, pn);
        pn[0] += p[0]; pn[1] += p[1]; pn[2] += p[2];

        mtv3(Rn, pn, pinv);
        pinv[0] = -pinv[0]; pinv[1] = -pinv[1]; pinv[2] = -pinv[2];

        mv3(R, &v[0], Rvl);
        mv3(R, &v[3], Rva);
        cross3(p, Rva, px);
    }

    // ---------------- Phase 6: Layer 3 via MFMA (n3 padded to 16) ----------------
    f32x4 c3[4];
#pragma unroll
    for (int rt = 0; rt < 4; ++rt) c3[rt] = (f32x4){0.f, 0.f, 0.f, 0.f};
#pragma unroll
    for (int kt = 0; kt < 4; ++kt) {
#pragma unroll
        for (int rt = 0; rt < 4; ++rt)
            c3[rt] = __builtin_amdgcn_mfma_f32_16x16x32_bf16(af3[rt][kt], b3f[kt], c3[rt], 0, 0, 0);
    }

    // ---------------- Phase 7: dv redistribute via dvt overlay (64 rows x 32B f32) ----------------
    float dvv[6];
    if (l15 < 6) {
#pragma unroll
        for (int rt = 0; rt < 4; ++rt)
#pragma unroll
            for (int r = 0; r < 4; ++r) {
                int row = rt * 16 + lg * 4 + r;
                *(float*)(dvt + row * 32 + l15 * 4) = c3[rt][r];
            }
    }
    __builtin_amdgcn_s_barrier();   // cross-lane LDS visibility (1-wave block; cheap)
    {
        const float* dr = (const float*)(dvt + lane * 32);
        dvv[0] = dr[0]; dvv[1] = dr[1]; dvv[2] = dr[2];
        dvv[3] = dr[3]; dvv[4] = dr[4]; dvv[5] = dr[5];
    }

    // ---------------- Phase 8: SE(3) tail (dv-dependent) ----------------
    float u6[6];
    u6[0] = Rvl[0] + px[0] + dvv[0];
    u6[1] = Rvl[1] + px[1] + dvv[1];
    u6[2] = Rvl[2] + px[2] + dvv[2];
    u6[3] = Rva[0] + dvv[3];
    u6[4] = Rva[1] + dvv[4];
    u6[5] = Rva[2] + dvv[5];

    float Rul[3], Rua[3];
    mtv3(Rn, &u6[0], Rul);
    mtv3(Rn, &u6[3], Rua);
    float pxu[3];
    cross3(pinv, Rua, pxu);
    float vn[6];
    vn[0] = Rul[0] + pxu[0];
    vn[1] = Rul[1] + pxu[1];
    vn[2] = Rul[2] + pxu[2];
    vn[3] = Rua[0];
    vn[4] = Rua[1];
    vn[5] = Rua[2];

    if (live) {
        float* s_next = out + (size_t)e * 18;
        s_next[0] = pn[0]; s_next[1] = pn[1]; s_next[2] = pn[2];
#pragma unroll
        for (int i = 0; i < 9; ++i) s_next[3 + i] = Rn[i];
#pragma unroll
        for (int i = 0; i < 6; ++i) s_next[12 + i] = vn[i];

        float* dvo = out + (size_t)K * 30 + (size_t)e * 6;
#pragma unroll
        for (int r = 0; r < 6; ++r) dvo[r] = dvv[r];
    }
}

extern "C" void kernel_launch(void* const* d_in, const int* in_sizes, int n_in,
                              void* d_out, int out_size, void* d_ws, size_t ws_size,
                              hipStream_t stream) {
    const float* s    = (const float*)d_in[0];
    const float* a    = (const float*)d_in[1];
    const float* h0   = (const float*)d_in[2];
    const float* W_ih = (const float*)d_in[3];
    const float* W_hh = (const float*)d_in[4];
    const float* W1   = (const float*)d_in[5];
    const float* W2   = (const float*)d_in[6];
    const float* W3   = (const float*)d_in[7];

    int K = in_sizes[0] / 18;
    unsigned short* ws = (unsigned short*)d_ws;

    weights_prep<<<(22528 + 255) / 256, 256, 0, stream>>>(W1, W2, W3, ws);

    int grid = (K + 63) / 64;
    auv_mfma12_kernel<<<grid, 64, 0, stream>>>(s, a, h0, W_ih, W_hh, ws,
                                               (float*)d_out, K);
}

// Round 16
// 52.921 us; speedup vs baseline: 1.2017x; 1.2017x over previous
//
#include <hip/hip_runtime.h>
#include <math.h>

typedef __attribute__((ext_vector_type(8))) short short8;
typedef __attribute__((ext_vector_type(4))) float f32x4;

#define DT_STEP 0.1f

static __device__ __forceinline__ unsigned bf16rne(float f) {
    unsigned u = __builtin_bit_cast(unsigned, f);
    return (u + 0x7fffu + ((u >> 16) & 1u)) >> 16;
}
static __device__ __forceinline__ unsigned short bf16pk1(float f) {
    unsigned r;
    asm("v_cvt_pk_bf16_f32 %0, %1, %1" : "=v"(r) : "v"(f));
    return (unsigned short)r;
}
static __device__ __forceinline__ unsigned bf16pk2(float lo, float hi) {
    unsigned r;
    asm("v_cvt_pk_bf16_f32 %0, %1, %2" : "=v"(r) : "v"(lo), "v"(hi));
    return r;
}
static __device__ __forceinline__ float tanh_fast(float v) {
    float e = __expf(2.0f * v);
    return 1.0f - 2.0f / (e + 1.0f);
}

static __device__ __forceinline__ void mm3(const float* A, const float* B, float* C) {
#pragma unroll
    for (int i = 0; i < 3; ++i)
#pragma unroll
        for (int j = 0; j < 3; ++j)
            C[i * 3 + j] = A[i * 3 + 0] * B[0 * 3 + j] + A[i * 3 + 1] * B[1 * 3 + j] + A[i * 3 + 2] * B[2 * 3 + j];
}
static __device__ __forceinline__ void mv3(const float* A, const float* x, float* y) {
#pragma unroll
    for (int i = 0; i < 3; ++i) y[i] = A[i * 3 + 0] * x[0] + A[i * 3 + 1] * x[1] + A[i * 3 + 2] * x[2];
}
static __device__ __forceinline__ void mtv3(const float* A, const float* x, float* y) {
#pragma unroll
    for (int i = 0; i < 3; ++i) y[i] = A[0 * 3 + i] * x[0] + A[1 * 3 + i] * x[1] + A[2 * 3 + i] * x[2];
}
static __device__ __forceinline__ void cross3(const float* p, const float* u, float* y) {
    y[0] = p[1] * u[2] - p[2] * u[1];
    y[1] = p[2] * u[0] - p[0] * u[2];
    y[2] = p[0] * u[1] - p[1] * u[0];
}

// ws layout (unsigned short elements) — verified r6/r7/r9/r10/r13:
//  [0,4096)      W1A: [n1=128][k=32] bf16, k>=12 zero
//  [4096,20480)  W2B: [n2=128][k=128] bf16
//  [20480,22528) W3B: [(kt*4+lg)*16 + n3pad]*8, n3pad<6 valid else 0
__global__ __launch_bounds__(256)
void weights_prep(const float* __restrict__ W1, const float* __restrict__ W2,
                  const float* __restrict__ W3, unsigned short* __restrict__ ws) {
    int i = blockIdx.x * 256 + threadIdx.x;
    if (i < 4096) {
        int n = i >> 5, k = i & 31;
        ws[i] = (k < 12) ? (unsigned short)bf16rne(W1[n * 12 + k]) : (unsigned short)0;
    } else if (i < 20480) {
        ws[i] = (unsigned short)bf16rne(W2[i - 4096]);
    } else if (i < 22528) {
        int j = i - 20480;
        int jj = j & 7;
        int l = (j >> 3) & 15;     // n3 (valid < 6)
        int kl = j >> 7;           // kt*4+lg
        int k = kl * 8 + jj;
        ws[i] = (l < 6) ? (unsigned short)bf16rne(W3[l * 128 + k]) : (unsigned short)0;
    }
}

// FINAL (r13 revert — best verified: 52.5us, absmax 0.0039, no spill, stable).
// r10 envelope (1-wave blocks, T14 preloads, SE3 overlap, xv reuse) with the
// r7 REGULAR-DS data path: XOR-swizzled l12, ds_read_b128 A-frags, scalar b16
// C-stores. Zero inline-asm LDS ops -> compiler inserts precise counted
// lgkmcnt waits and pipelines reads into MFMAs; no manual drains needed
// (r11 race was tr-asm-specific; r15 fusion spilled — both reverted).
// LDS: l12 [0,16384) + h1t [16384,18432) = 18432 B -> 8 blocks/CU.
__global__ __launch_bounds__(64, 3)
void auv_mfma10_kernel(const float* __restrict__ s, const float* __restrict__ a,
                       const float* __restrict__ h0, const float* __restrict__ W_ih,
                       const float* __restrict__ W_hh, const unsigned short* __restrict__ Wbf,
                       float* __restrict__ out, int K)
{
    __shared__ __align__(16) char lds[18432];
    const int lane = threadIdx.x & 63;
    const int l15  = lane & 15;
    const int lg   = lane >> 4;

    char* l12 = &lds[0];            // 64 rows x 256B, XOR swizzle ((row&15)<<4)
    char* h1t = &lds[16384];        // 64 rows x 32B
    char* dvt = &lds[0];            // overlay after af3 reads (compiler-ordered)

    const unsigned short* W1A = Wbf;
    const unsigned short* W2B = Wbf + 4096;
    const unsigned short* W3B = Wbf + 20480;

    const int e_raw = blockIdx.x * 64 + lane;
    const int e  = e_raw < K ? e_raw : K - 1;
    const bool live = e_raw < K;

    const float* srow = s  + (size_t)e * 18;
    const float* arow = a  + (size_t)e * 6;
    const float* hrow = h0 + (size_t)e * 12;

    // ---------------- Phase 1: RNN (scalar; W rows wave-uniform -> s_load) ----------------
    float pv3[3];
    pv3[0] = srow[0]; pv3[1] = srow[1]; pv3[2] = srow[2];
    float xv[21];
#pragma unroll
    for (int i = 0; i < 15; ++i) xv[i] = srow[3 + i];
#pragma unroll
    for (int i = 0; i < 6; ++i)  xv[15 + i] = arow[i];
    float h0v[12];
#pragma unroll
    for (int i = 0; i < 12; ++i) h0v[i] = hrow[i];

    float h1v[12];
#pragma unroll
    for (int j = 0; j < 12; ++j) {
        float acc = 0.f;
        const float* wih = W_ih + j * 21;
#pragma unroll
        for (int i = 0; i < 21; ++i) acc = fmaf(wih[i], xv[i], acc);
        const float* whh = W_hh + j * 12;
#pragma unroll
        for (int i = 0; i < 12; ++i) acc = fmaf(whh[i], h0v[i], acc);
        h1v[j] = tanh_fast(acc);
    }

    if (live) {
        float4* h4 = (float4*)(out + (size_t)K * 18 + (size_t)e * 12);
        h4[0] = make_float4(h1v[0], h1v[1], h1v[2], h1v[3]);
        h4[1] = make_float4(h1v[4], h1v[5], h1v[6], h1v[7]);
        h4[2] = make_float4(h1v[8], h1v[9], h1v[10], h1v[11]);
    }

    // T14: issue W2B nt=0 B-frag loads NOW (consumed in P4)
    short8 bfr[4];
#pragma unroll
    for (int kt = 0; kt < 4; ++kt)
        bfr[kt] = __builtin_bit_cast(short8,
            *(const uint4*)(W2B + (l15 * 128 + kt * 32 + lg * 8)));

    // h1 -> h1t: row=lane, 16 bf16 (12 valid + 4 zero); chunk swizzle by (row&1)
    {
        unsigned p0 = bf16pk2(h1v[0], h1v[1]);
        unsigned p1 = bf16pk2(h1v[2], h1v[3]);
        unsigned p2 = bf16pk2(h1v[4], h1v[5]);
        unsigned p3 = bf16pk2(h1v[6], h1v[7]);
        unsigned p4 = bf16pk2(h1v[8], h1v[9]);
        unsigned p5 = bf16pk2(h1v[10], h1v[11]);
        int rq = (lane & 1) << 4;
        *(uint4*)(h1t + lane * 32 + (0 ^ rq))  = make_uint4(p0, p1, p2, p3);
        *(uint4*)(h1t + lane * 32 + (16 ^ rq)) = make_uint4(p4, p5, 0u, 0u);
    }

    const short8 zfrag = {0, 0, 0, 0, 0, 0, 0, 0};

    // ---------------- Phase 2: Layer 1 via MFMA (K=32 zero-padded) ----------------
    short8 af1[4];
#pragma unroll
    for (int rt = 0; rt < 4; ++rt) {
        af1[rt] = zfrag;
        if (lg < 2) {
            int row = rt * 16 + l15;
            af1[rt] = __builtin_bit_cast(short8,
                *(const uint4*)(h1t + row * 32 + ((lg * 16) ^ ((row & 1) << 4))));
        }
    }
#pragma unroll 1
    for (int nt = 0; nt < 8; ++nt) {
        short8 b1 = __builtin_bit_cast(short8,
            *(const uint4*)(W1A + ((nt * 16 + l15) * 32 + lg * 8)));
#pragma unroll
        for (int rt = 0; rt < 4; ++rt) {
            f32x4 z = {0.f, 0.f, 0.f, 0.f};
            f32x4 c1 = __builtin_amdgcn_mfma_f32_16x16x32_bf16(af1[rt], b1, z, 0, 0, 0);
#pragma unroll
            for (int r = 0; r < 4; ++r) {
                int row = rt * 16 + lg * 4 + r;
                float v = c1[r];
                v = fmaxf(v, 0.1f * v);
                *(unsigned short*)(l12 + row * 256 +
                    (((nt * 16 + l15) * 2) ^ ((row & 15) << 4))) = bf16pk1(v);
            }
        }
    }

    // ---------------- Phase 3: A2 fragments (regular ds_read_b128) ----------------
    short8 af2[4][4];
#pragma unroll
    for (int rt = 0; rt < 4; ++rt)
#pragma unroll
        for (int kt = 0; kt < 4; ++kt) {
            int row = rt * 16 + l15;
            af2[rt][kt] = __builtin_bit_cast(short8,
                *(const uint4*)(l12 + row * 256 + ((kt * 64 + lg * 16) ^ ((row & 15) << 4))));
        }

    // T14: W3B loads issued early (consumed in P6)
    short8 b3f[4];
#pragma unroll
    for (int kt = 0; kt < 4; ++kt)
        b3f[kt] = __builtin_bit_cast(short8,
            *(const uint4*)(W3B + (((kt * 4 + lg) * 16 + l15) * 8)));

    // ---------------- Phase 4: Layer 2 via MFMA (bfr preloaded; bnext prefetch) ----------------
#pragma unroll 1
    for (int nt = 0; nt < 8; ++nt) {
        short8 bnext[4];
        if (nt < 7) {
#pragma unroll
            for (int kt = 0; kt < 4; ++kt)
                bnext[kt] = __builtin_bit_cast(short8,
                    *(const uint4*)(W2B + (((nt + 1) * 16 + l15) * 128 + kt * 32 + lg * 8)));
        }
#pragma unroll
        for (int rt = 0; rt < 4; ++rt) {
            f32x4 c2 = {0.f, 0.f, 0.f, 0.f};
#pragma unroll
            for (int kt = 0; kt < 4; ++kt)
                c2 = __builtin_amdgcn_mfma_f32_16x16x32_bf16(af2[rt][kt], bfr[kt], c2, 0, 0, 0);
#pragma unroll
            for (int r = 0; r < 4; ++r) {
                int row = rt * 16 + lg * 4 + r;
                float v = c2[r];
                v = fmaxf(v, 0.1f * v);
                *(unsigned short*)(l12 + row * 256 +
                    (((nt * 16 + l15) * 2) ^ ((row & 15) << 4))) = bf16pk1(v);
            }
        }
#pragma unroll
        for (int kt = 0; kt < 4; ++kt) bfr[kt] = bnext[kt];
    }

    // ---------------- Phase 5: A3 fragments (regular reads) + SE3 part 1 ----------------
    short8 af3[4][4];
#pragma unroll
    for (int rt = 0; rt < 4; ++rt)
#pragma unroll
        for (int kt = 0; kt < 4; ++kt) {
            int row = rt * 16 + l15;
            af3[rt][kt] = __builtin_bit_cast(short8,
                *(const uint4*)(l12 + row * 256 + ((kt * 64 + lg * 16) ^ ((row & 15) << 4))));
        }

    // dv-independent SE(3) work (R,v from xv; p from pv3 — no s re-read)
    const float* v = &xv[9];
    const float* p = pv3;
    const float* R = &xv[0];

    float Rn[9], pn[3], pinv[3], Rvl[3], Rva[3], px[3];
    {
        float rho[3] = {v[0] * DT_STEP, v[1] * DT_STEP, v[2] * DT_STEP};
        float phi[3] = {v[3] * DT_STEP, v[4] * DT_STEP, v[5] * DT_STEP};
        float th2 = phi[0] * phi[0] + phi[1] * phi[1] + phi[2] * phi[2];

        float A, B, C;
        if (th2 < 1e-8f) {
            A = 1.0f - th2 * (1.0f / 6.0f);
            B = 0.5f - th2 * (1.0f / 24.0f);
            C = (1.0f / 6.0f) - th2 * (1.0f / 120.0f);
        } else {
            float th = sqrtf(th2);
            float sn = sinf(th), cs = cosf(th);
            A = sn / th;
            B = (1.0f - cs) / th2;
            C = (th - sn) / (th2 * th);
        }

        float S[9] = {0.f, -phi[2], phi[1], phi[2], 0.f, -phi[0], -phi[1], phi[0], 0.f};
        float S2[9];
        mm3(S, S, S2);

        float Re[9], V[9];
#pragma unroll
        for (int i = 0; i < 9; ++i) {
            float I = (i == 0 || i == 4 || i == 8) ? 1.0f : 0.0f;
            Re[i] = I + A * S[i] + B * S2[i];
            V[i]  = I + B * S[i] + C * S2[i];
        }

        float pe[3];
        mv3(V, rho, pe);
        mm3(R, Re, Rn);
        mv3(R, pe, pn);
        pn[0] += p[0]; pn[1] += p[1]; pn[2] += p[2];

        mtv3(Rn, pn, pinv);
        pinv[0] = -pinv[0]; pinv[1] = -pinv[1]; pinv[2] = -pinv[2];

        mv3(R, &v[0], Rvl);
        mv3(R, &v[3], Rva);
        cross3(p, Rva, px);
    }

    // ---------------- Phase 6: Layer 3 via MFMA (n3 padded to 16) ----------------
    f32x4 c3[4];
#pragma unroll
    for (int rt = 0; rt < 4; ++rt) c3[rt] = (f32x4){0.f, 0.f, 0.f, 0.f};
#pragma unroll
    for (int kt = 0; kt < 4; ++kt) {
#pragma unroll
        for (int rt = 0; rt < 4; ++rt)
            c3[rt] = __builtin_amdgcn_mfma_f32_16x16x32_bf16(af3[rt][kt], b3f[kt], c3[rt], 0, 0, 0);
    }

    // ---------------- Phase 7: dv redistribute via dvt overlay (64 rows x 32B f32) ----------------
    float dvv[6];
    if (l15 < 6) {
#pragma unroll
        for (int rt = 0; rt < 4; ++rt)
#pragma unroll
            for (int r = 0; r < 4; ++r) {
                int row = rt * 16 + lg * 4 + r;
                *(float*)(dvt + row * 32 + l15 * 4) = c3[rt][r];
            }
    }
    __builtin_amdgcn_s_barrier();   // single-wave block: cheap; guarantees LDS visibility
    {
        const float* dr = (const float*)(dvt + lane * 32);
        dvv[0] = dr[0]; dvv[1] = dr[1]; dvv[2] = dr[2];
        dvv[3] = dr[3]; dvv[4] = dr[4]; dvv[5] = dr[5];
    }

    // ---------------- Phase 8: SE(3) tail (dv-dependent) ----------------
    float u6[6];
    u6[0] = Rvl[0] + px[0] + dvv[0];
    u6[1] = Rvl[1] + px[1] + dvv[1];
    u6[2] = Rvl[2] + px[2] + dvv[2];
    u6[3] = Rva[0] + dvv[3];
    u6[4] = Rva[1] + dvv[4];
    u6[5] = Rva[2] + dvv[5];

    float Rul[3], Rua[3];
    mtv3(Rn, &u6[0], Rul);
    mtv3(Rn, &u6[3], Rua);
    float pxu[3];
    cross3(pinv, Rua, pxu);
    float vn[6];
    vn[0] = Rul[0] + pxu[0];
    vn[1] = Rul[1] + pxu[1];
    vn[2] = Rul[2] + pxu[2];
    vn[3] = Rua[0];
    vn[4] = Rua[1];
    vn[5] = Rua[2];

    if (live) {
        float* s_next = out + (size_t)e * 18;
        s_next[0] = pn[0]; s_next[1] = pn[1]; s_next[2] = pn[2];
#pragma unroll
        for (int i = 0; i < 9; ++i) s_next[3 + i] = Rn[i];
#pragma unroll
        for (int i = 0; i < 6; ++i) s_next[12 + i] = vn[i];

        float* dvo = out + (size_t)K * 30 + (size_t)e * 6;
#pragma unroll
        for (int r = 0; r < 6; ++r) dvo[r] = dvv[r];
    }
}

extern "C" void kernel_launch(void* const* d_in, const int* in_sizes, int n_in,
                              void* d_out, int out_size, void* d_ws, size_t ws_size,
                              hipStream_t stream) {
    const float* s    = (const float*)d_in[0];
    const float* a    = (const float*)d_in[1];
    const float* h0   = (const float*)d_in[2];
    const float* W_ih = (const float*)d_in[3];
    const float* W_hh = (const float*)d_in[4];
    const float* W1   = (const float*)d_in[5];
    const float* W2   = (const float*)d_in[6];
    const float* W3   = (const float*)d_in[7];

    int K = in_sizes[0] / 18;
    unsigned short* ws = (unsigned short*)d_ws;

    weights_prep<<<(22528 + 255) / 256, 256, 0, stream>>>(W1, W2, W3, ws);

    int grid = (K + 63) / 64;
    auv_mfma10_kernel<<<grid, 64, 0, stream>>>(s, a, h0, W_ih, W_hh, ws,
                                               (float*)d_out, K);
}

// Round 17
// 47.147 us; speedup vs baseline: 1.3488x; 1.1225x over previous
//
#include <hip/hip_runtime.h>
#include <math.h>

typedef __attribute__((ext_vector_type(8))) short short8;
typedef __attribute__((ext_vector_type(4))) float f32x4;

#define DT_STEP 0.1f

static __device__ __forceinline__ unsigned bf16rne(float f) {
    unsigned u = __builtin_bit_cast(unsigned, f);
    return (u + 0x7fffu + ((u >> 16) & 1u)) >> 16;
}
static __device__ __forceinline__ unsigned short bf16pk1(float f) {
    unsigned r;
    asm("v_cvt_pk_bf16_f32 %0, %1, %1" : "=v"(r) : "v"(f));
    return (unsigned short)r;
}
static __device__ __forceinline__ unsigned bf16pk2(float lo, float hi) {
    unsigned r;
    asm("v_cvt_pk_bf16_f32 %0, %1, %2" : "=v"(r) : "v"(lo), "v"(hi));
    return r;
}
static __device__ __forceinline__ float tanh_fast(float v) {
    float e = __expf(2.0f * v);
    return 1.0f - 2.0f / (e + 1.0f);
}

static __device__ __forceinline__ void mm3(const float* A, const float* B, float* C) {
#pragma unroll
    for (int i = 0; i < 3; ++i)
#pragma unroll
        for (int j = 0; j < 3; ++j)
            C[i * 3 + j] = A[i * 3 + 0] * B[0 * 3 + j] + A[i * 3 + 1] * B[1 * 3 + j] + A[i * 3 + 2] * B[2 * 3 + j];
}
static __device__ __forceinline__ void mv3(const float* A, const float* x, float* y) {
#pragma unroll
    for (int i = 0; i < 3; ++i) y[i] = A[i * 3 + 0] * x[0] + A[i * 3 + 1] * x[1] + A[i * 3 + 2] * x[2];
}
static __device__ __forceinline__ void mtv3(const float* A, const float* x, float* y) {
#pragma unroll
    for (int i = 0; i < 3; ++i) y[i] = A[0 * 3 + i] * x[0] + A[1 * 3 + i] * x[1] + A[2 * 3 + i] * x[2];
}
static __device__ __forceinline__ void cross3(const float* p, const float* u, float* y) {
    y[0] = p[1] * u[2] - p[2] * u[1];
    y[1] = p[2] * u[0] - p[0] * u[2];
    y[2] = p[0] * u[1] - p[1] * u[0];
}

// ws layout (unsigned short elements) — regions 0-2 verified r6/r7/r9/r10/r13:
//  [0,4096)       W1A: [n1=128][k=32] bf16, k>=12 zero
//  [4096,20480)   W2B: [n2=128][k=128] bf16
//  [20480,22528)  W3B: [(kt*4+lg)*16 + n3pad]*8, n3pad<6 valid else 0
//  [22528,23552)  WRN: [n=16][k=64] combined RNN weight: k<21 W_ih, 21<=k<33 W_hh, else 0; n>=12 zero
__global__ __launch_bounds__(256)
void weights_prep(const float* __restrict__ W1, const float* __restrict__ W2,
                  const float* __restrict__ W3, const float* __restrict__ W_ih,
                  const float* __restrict__ W_hh, unsigned short* __restrict__ ws) {
    int i = blockIdx.x * 256 + threadIdx.x;
    if (i < 4096) {
        int n = i >> 5, k = i & 31;
        ws[i] = (k < 12) ? (unsigned short)bf16rne(W1[n * 12 + k]) : (unsigned short)0;
    } else if (i < 20480) {
        ws[i] = (unsigned short)bf16rne(W2[i - 4096]);
    } else if (i < 22528) {
        int j = i - 20480;
        int jj = j & 7;
        int l = (j >> 3) & 15;     // n3 (valid < 6)
        int kl = j >> 7;           // kt*4+lg
        int k = kl * 8 + jj;
        ws[i] = (l < 6) ? (unsigned short)bf16rne(W3[l * 128 + k]) : (unsigned short)0;
    } else if (i < 23552) {
        int j = i - 22528;
        int n = j >> 6;            // 0..15 (valid < 12)
        int k = j & 63;            // 0..63 (valid < 33)
        float val = 0.0f;
        if (n < 12) {
            if (k < 21)      val = W_ih[n * 21 + k];
            else if (k < 33) val = W_hh[n * 12 + (k - 21)];
        }
        ws[i] = (n < 12 && k < 33) ? (unsigned short)bf16rne(val) : (unsigned short)0;
    }
}

// r13 base (verified 52.5us) with the RNN moved onto MFMA:
//  h1 = tanh([x|h0] @ [W_ih|W_hh]^T): M=64 elem, N=16 (12 valid), K=64 (33 valid).
//  x-tile: row=element, 64 bf16/row (128B), XOR swizzle (row&7)<<4 per 16B slot
//  (overlays l12 [0,8192), dead before P2 stores — in-order DS, r13 discipline).
//  B-frags from WRN (same [n][k] indexing as verified W2B). C layout identical
//  to all verified layers. tanh on C in-register; h1 -> h1t bf16 (r13 addrs;
//  n>=12 naturally 0) + f32 scratch (stride 48) for coalesced hN readback.
// Everything from P2 on is byte-identical to r13.
__global__ __launch_bounds__(64, 3)
void auv_mfma13_kernel(const float* __restrict__ s, const float* __restrict__ a,
                       const float* __restrict__ h0, const unsigned short* __restrict__ Wbf,
                       float* __restrict__ out, int K)
{
    __shared__ __align__(16) char lds[18432];
    const int lane = threadIdx.x & 63;
    const int l15  = lane & 15;
    const int lg   = lane >> 4;

    char* l12 = &lds[0];            // 64 rows x 256B, XOR swizzle ((row&15)<<4)
    char* xt  = &lds[0];            // overlay: x-tile 64 rows x 128B
    char* hf  = &lds[8192];         // overlay: h1 f32, 64 rows x 48B
    char* h1t = &lds[16384];        // 64 rows x 32B
    char* dvt = &lds[0];            // overlay after af3 reads

    const unsigned short* W1A = Wbf;
    const unsigned short* W2B = Wbf + 4096;
    const unsigned short* W3B = Wbf + 20480;
    const unsigned short* WRN = Wbf + 22528;

    const int e_raw = blockIdx.x * 64 + lane;
    const int e  = e_raw < K ? e_raw : K - 1;
    const bool live = e_raw < K;

    const float* srow = s  + (size_t)e * 18;
    const float* arow = a  + (size_t)e * 6;
    const float* hrow = h0 + (size_t)e * 12;

    // ---------------- Phase 1: gather inputs ----------------
    float pv3[3];
    pv3[0] = srow[0]; pv3[1] = srow[1]; pv3[2] = srow[2];
    float xv[21];
#pragma unroll
    for (int i = 0; i < 15; ++i) xv[i] = srow[3 + i];
#pragma unroll
    for (int i = 0; i < 6; ++i)  xv[15 + i] = arow[i];
    float h0v[12];
#pragma unroll
    for (int i = 0; i < 12; ++i) h0v[i] = hrow[i];

    // T14: issue RNN B-frags + W2B nt=0 B-frags early (consumed below / in P4)
    short8 brn[2];
#pragma unroll
    for (int kt = 0; kt < 2; ++kt)
        brn[kt] = __builtin_bit_cast(short8,
            *(const uint4*)(WRN + (l15 * 64 + kt * 32 + lg * 8)));
    short8 bfr[4];
#pragma unroll
    for (int kt = 0; kt < 4; ++kt)
        bfr[kt] = __builtin_bit_cast(short8,
            *(const uint4*)(W2B + (l15 * 128 + kt * 32 + lg * 8)));

    // ---------------- RNN via MFMA: stage x-tile ----------------
    {
        unsigned w[20];
#pragma unroll
        for (int i = 0; i < 10; ++i) w[i] = bf16pk2(xv[2 * i], xv[2 * i + 1]);
        w[10] = bf16pk2(xv[20], h0v[0]);
#pragma unroll
        for (int j = 0; j < 5; ++j) w[11 + j] = bf16pk2(h0v[1 + 2 * j], h0v[2 + 2 * j]);
        w[16] = bf16pk2(h0v[11], 0.0f);
        w[17] = 0u; w[18] = 0u; w[19] = 0u;
        const int swz = (lane & 7) << 4;
        *(uint4*)(xt + lane * 128 + ((0)  ^ swz)) = make_uint4(w[0],  w[1],  w[2],  w[3]);
        *(uint4*)(xt + lane * 128 + ((16) ^ swz)) = make_uint4(w[4],  w[5],  w[6],  w[7]);
        *(uint4*)(xt + lane * 128 + ((32) ^ swz)) = make_uint4(w[8],  w[9],  w[10], w[11]);
        *(uint4*)(xt + lane * 128 + ((48) ^ swz)) = make_uint4(w[12], w[13], w[14], w[15]);
        *(uint4*)(xt + lane * 128 + ((64) ^ swz)) = make_uint4(w[16], w[17], w[18], w[19]);
        *(uint4*)(xt + lane * 128 + ((80) ^ swz)) = make_uint4(0u, 0u, 0u, 0u);
        *(uint4*)(xt + lane * 128 + ((96) ^ swz)) = make_uint4(0u, 0u, 0u, 0u);
        *(uint4*)(xt + lane * 128 + ((112) ^ swz)) = make_uint4(0u, 0u, 0u, 0u);
    }

    // A-frags from x-tile (regular ds_read_b128; in-order after the writes)
    short8 afx[4][2];
#pragma unroll
    for (int rt = 0; rt < 4; ++rt)
#pragma unroll
        for (int kt = 0; kt < 2; ++kt) {
            int row = rt * 16 + l15;
            afx[rt][kt] = __builtin_bit_cast(short8,
                *(const uint4*)(xt + row * 128 + ((kt * 64 + lg * 16) ^ ((row & 7) << 4))));
        }

    // 8 MFMAs: h1pre = [x|h0] @ WRN^T
    f32x4 cr[4];
#pragma unroll
    for (int rt = 0; rt < 4; ++rt) {
        cr[rt] = (f32x4){0.f, 0.f, 0.f, 0.f};
#pragma unroll
        for (int kt = 0; kt < 2; ++kt)
            cr[rt] = __builtin_amdgcn_mfma_f32_16x16x32_bf16(afx[rt][kt], brn[kt], cr[rt], 0, 0, 0);
    }

    // tanh + h1 stores: h1t bf16 (r13 addresses; l15>=12 stores tanh(0)=0)
    // and hf f32 (stride 48) for the hN readback
#pragma unroll
    for (int rt = 0; rt < 4; ++rt)
#pragma unroll
        for (int r = 0; r < 4; ++r) {
            int row = rt * 16 + lg * 4 + r;
            float hv = tanh_fast(cr[rt][r]);
            *(unsigned short*)(h1t + row * 32 + ((l15 * 2) ^ ((row & 1) << 4))) = bf16pk1(hv);
            if (l15 < 12) *(float*)(hf + row * 48 + l15 * 4) = hv;
        }

    // hN readback (coalesced-ish) + global write
    {
        float4 q0 = *(const float4*)(hf + lane * 48);
        float4 q1 = *(const float4*)(hf + lane * 48 + 16);
        float4 q2 = *(const float4*)(hf + lane * 48 + 32);
        if (live) {
            float4* h4 = (float4*)(out + (size_t)K * 18 + (size_t)e * 12);
            h4[0] = q0; h4[1] = q1; h4[2] = q2;
        }
    }

    const short8 zfrag = {0, 0, 0, 0, 0, 0, 0, 0};

    // ---------------- Phase 2: Layer 1 via MFMA (K=32 zero-padded) ----------------
    short8 af1[4];
#pragma unroll
    for (int rt = 0; rt < 4; ++rt) {
        af1[rt] = zfrag;
        if (lg < 2) {
            int row = rt * 16 + l15;
            af1[rt] = __builtin_bit_cast(short8,
                *(const uint4*)(h1t + row * 32 + ((lg * 16) ^ ((row & 1) << 4))));
        }
    }
#pragma unroll 1
    for (int nt = 0; nt < 8; ++nt) {
        short8 b1 = __builtin_bit_cast(short8,
            *(const uint4*)(W1A + ((nt * 16 + l15) * 32 + lg * 8)));
#pragma unroll
        for (int rt = 0; rt < 4; ++rt) {
            f32x4 z = {0.f, 0.f, 0.f, 0.f};
            f32x4 c1 = __builtin_amdgcn_mfma_f32_16x16x32_bf16(af1[rt], b1, z, 0, 0, 0);
#pragma unroll
            for (int r = 0; r < 4; ++r) {
                int row = rt * 16 + lg * 4 + r;
                float v = c1[r];
                v = fmaxf(v, 0.1f * v);
                *(unsigned short*)(l12 + row * 256 +
                    (((nt * 16 + l15) * 2) ^ ((row & 15) << 4))) = bf16pk1(v);
            }
        }
    }

    // ---------------- Phase 3: A2 fragments (regular ds_read_b128) ----------------
    short8 af2[4][4];
#pragma unroll
    for (int rt = 0; rt < 4; ++rt)
#pragma unroll
        for (int kt = 0; kt < 4; ++kt) {
            int row = rt * 16 + l15;
            af2[rt][kt] = __builtin_bit_cast(short8,
                *(const uint4*)(l12 + row * 256 + ((kt * 64 + lg * 16) ^ ((row & 15) << 4))));
        }

    // T14: W3B loads issued early (consumed in P6)
    short8 b3f[4];
#pragma unroll
    for (int kt = 0; kt < 4; ++kt)
        b3f[kt] = __builtin_bit_cast(short8,
            *(const uint4*)(W3B + (((kt * 4 + lg) * 16 + l15) * 8)));

    // ---------------- Phase 4: Layer 2 via MFMA (bfr preloaded; bnext prefetch) ----------------
#pragma unroll 1
    for (int nt = 0; nt < 8; ++nt) {
        short8 bnext[4];
        if (nt < 7) {
#pragma unroll
            for (int kt = 0; kt < 4; ++kt)
                bnext[kt] = __builtin_bit_cast(short8,
                    *(const uint4*)(W2B + (((nt + 1) * 16 + l15) * 128 + kt * 32 + lg * 8)));
        }
#pragma unroll
        for (int rt = 0; rt < 4; ++rt) {
            f32x4 c2 = {0.f, 0.f, 0.f, 0.f};
#pragma unroll
            for (int kt = 0; kt < 4; ++kt)
                c2 = __builtin_amdgcn_mfma_f32_16x16x32_bf16(af2[rt][kt], bfr[kt], c2, 0, 0, 0);
#pragma unroll
            for (int r = 0; r < 4; ++r) {
                int row = rt * 16 + lg * 4 + r;
                float v = c2[r];
                v = fmaxf(v, 0.1f * v);
                *(unsigned short*)(l12 + row * 256 +
                    (((nt * 16 + l15) * 2) ^ ((row & 15) << 4))) = bf16pk1(v);
            }
        }
#pragma unroll
        for (int kt = 0; kt < 4; ++kt) bfr[kt] = bnext[kt];
    }

    // ---------------- Phase 5: A3 fragments (regular reads) + SE3 part 1 ----------------
    short8 af3[4][4];
#pragma unroll
    for (int rt = 0; rt < 4; ++rt)
#pragma unroll
        for (int kt = 0; kt < 4; ++kt) {
            int row = rt * 16 + l15;
            af3[rt][kt] = __builtin_bit_cast(short8,
                *(const uint4*)(l12 + row * 256 + ((kt * 64 + lg * 16) ^ ((row & 15) << 4))));
        }

    // dv-independent SE(3) work (R,v from xv; p from pv3 — no s re-read)
    const float* v = &xv[9];
    const float* p = pv3;
    const float* R = &xv[0];

    float Rn[9], pn[3], pinv[3], Rvl[3], Rva[3], px[3];
    {
        float rho[3] = {v[0] * DT_STEP, v[1] * DT_STEP, v[2] * DT_STEP};
        float phi[3] = {v[3] * DT_STEP, v[4] * DT_STEP, v[5] * DT_STEP};
        float th2 = phi[0] * phi[0] + phi[1] * phi[1] + phi[2] * phi[2];

        float A, B, C;
        if (th2 < 1e-8f) {
            A = 1.0f - th2 * (1.0f / 6.0f);
            B = 0.5f - th2 * (1.0f / 24.0f);
            C = (1.0f / 6.0f) - th2 * (1.0f / 120.0f);
        } else {
            float th = sqrtf(th2);
            float sn = sinf(th), cs = cosf(th);
            A = sn / th;
            B = (1.0f - cs) / th2;
            C = (th - sn) / (th2 * th);
        }

        float S[9] = {0.f, -phi[2], phi[1], phi[2], 0.f, -phi[0], -phi[1], phi[0], 0.f};
        float S2[9];
        mm3(S, S, S2);

        float Re[9], V[9];
#pragma unroll
        for (int i = 0; i < 9; ++i) {
            float I = (i == 0 || i == 4 || i == 8) ? 1.0f : 0.0f;
            Re[i] = I + A * S[i] + B * S2[i];
            V[i]  = I + B * S[i] + C * S2[i];
        }

        float pe[3];
        mv3(V, rho, pe);
        mm3(R, Re, Rn);
        mv3(R, pe, pn);
        pn[0] += p[0]; pn[1] += p[1]; pn[2] += p[2];

        mtv3(Rn, pn, pinv);
        pinv[0] = -pinv[0]; pinv[1] = -pinv[1]; pinv[2] = -pinv[2];

        mv3(R, &v[0], Rvl);
        mv3(R, &v[3], Rva);
        cross3(p, Rva, px);
    }

    // ---------------- Phase 6: Layer 3 via MFMA (n3 padded to 16) ----------------
    f32x4 c3[4];
#pragma unroll
    for (int rt = 0; rt < 4; ++rt) c3[rt] = (f32x4){0.f, 0.f, 0.f, 0.f};
#pragma unroll
    for (int kt = 0; kt < 4; ++kt) {
#pragma unroll
        for (int rt = 0; rt < 4; ++rt)
            c3[rt] = __builtin_amdgcn_mfma_f32_16x16x32_bf16(af3[rt][kt], b3f[kt], c3[rt], 0, 0, 0);
    }

    // ---------------- Phase 7: dv redistribute via dvt overlay (64 rows x 32B f32) ----------------
    float dvv[6];
    if (l15 < 6) {
#pragma unroll
        for (int rt = 0; rt < 4; ++rt)
#pragma unroll
            for (int r = 0; r < 4; ++r) {
                int row = rt * 16 + lg * 4 + r;
                *(float*)(dvt + row * 32 + l15 * 4) = c3[rt][r];
            }
    }
    __builtin_amdgcn_s_barrier();   // single-wave block: cheap; guarantees LDS visibility
    {
        const float* dr = (const float*)(dvt + lane * 32);
        dvv[0] = dr[0]; dvv[1] = dr[1]; dvv[2] = dr[2];
        dvv[3] = dr[3]; dvv[4] = dr[4]; dvv[5] = dr[5];
    }

    // ---------------- Phase 8: SE(3) tail (dv-dependent) ----------------
    float u6[6];
    u6[0] = Rvl[0] + px[0] + dvv[0];
    u6[1] = Rvl[1] + px[1] + dvv[1];
    u6[2] = Rvl[2] + px[2] + dvv[2];
    u6[3] = Rva[0] + dvv[3];
    u6[4] = Rva[1] + dvv[4];
    u6[5] = Rva[2] + dvv[5];

    float Rul[3], Rua[3];
    mtv3(Rn, &u6[0], Rul);
    mtv3(Rn, &u6[3], Rua);
    float pxu[3];
    cross3(pinv, Rua, pxu);
    float vn[6];
    vn[0] = Rul[0] + pxu[0];
    vn[1] = Rul[1] + pxu[1];
    vn[2] = Rul[2] + pxu[2];
    vn[3] = Rua[0];
    vn[4] = Rua[1];
    vn[5] = Rua[2];

    if (live) {
        float* s_next = out + (size_t)e * 18;
        s_next[0] = pn[0]; s_next[1] = pn[1]; s_next[2] = pn[2];
#pragma unroll
        for (int i = 0; i < 9; ++i) s_next[3 + i] = Rn[i];
#pragma unroll
        for (int i = 0; i < 6; ++i) s_next[12 + i] = vn[i];

        float* dvo = out + (size_t)K * 30 + (size_t)e * 6;
#pragma unroll
        for (int r = 0; r < 6; ++r) dvo[r] = dvv[r];
    }
}

extern "C" void kernel_launch(void* const* d_in, const int* in_sizes, int n_in,
                              void* d_out, int out_size, void* d_ws, size_t ws_size,
                              hipStream_t stream) {
    const float* s    = (const float*)d_in[0];
    const float* a    = (const float*)d_in[1];
    const float* h0   = (const float*)d_in[2];
    const float* W_ih = (const float*)d_in[3];
    const float* W_hh = (const float*)d_in[4];
    const float* W1   = (const float*)d_in[5];
    const float* W2   = (const float*)d_in[6];
    const float* W3   = (const float*)d_in[7];

    int K = in_sizes[0] / 18;
    unsigned short* ws = (unsigned short*)d_ws;

    weights_prep<<<(23552 + 255) / 256, 256, 0, stream>>>(W1, W2, W3, W_ih, W_hh, ws);

    int grid = (K + 63) / 64;
    auv_mfma13_kernel<<<grid, 64, 0, stream>>>(s, a, h0, ws, (float*)d_out, K);
}